// Round 6
// baseline (463.799 us; speedup 1.0000x reference)
//
#include <hip/hip_runtime.h>
#include <hip/hip_bf16.h>

#define NN 8192
#define DD 128

typedef __attribute__((ext_vector_type(8))) short short8;
typedef __attribute__((ext_vector_type(4))) float f32x4;
typedef unsigned int u32;

__device__ __forceinline__ ushort f2bf(float f) {
    __hip_bfloat16 h = __float2bfloat16(f);
    return *(ushort*)&h;
}
__device__ __forceinline__ float asf(u32 u) {
    union { u32 i; float f; } v; v.i = u; return v.f;
}

// async 16B/lane global->LDS; LDS dest is wave-uniform base + lane*16.
__device__ __forceinline__ void async_ld16(const void* g, void* l) {
    __builtin_amdgcn_global_load_lds(
        (const __attribute__((address_space(1))) u32*)g,
        (__attribute__((address_space(3))) u32*)l, 16, 0, 0);
}

// ---------------- K1f: Wh = X@Ws fused with transpose + per-row scalars ------
// 256 blocks x 256 thr; 32 rows/block. Wh never hits global: acc -> LDS
// (overlaid on lWs) -> WhT(bf16), s1/s2 dots, C1/C1s/E2bf.
__global__ __launch_bounds__(256) void k1_fused(
    const float* __restrict__ X, const float* __restrict__ Ws,
    const float* __restrict__ a, ushort* __restrict__ WhT,
    float* __restrict__ C1, float* __restrict__ C1s, u32* __restrict__ E2bf) {
    __shared__ float lWs[128 * 132];   // 67584 B; overlaid by lT[128][33] after use
    __shared__ float lX[32 * 132];
    __shared__ float la[256];
    int t = threadIdx.x, bx = blockIdx.x;
    int i0 = bx * 32;
    const float4* Ws4 = (const float4*)Ws;
    const float4* X4 = (const float4*)X;
    la[t] = a[t];
    for (int j = 0; j < 16; ++j) {
        int u = j * 256 + t;
        int k = u >> 5, c4 = u & 31;
        *(float4*)&lWs[k * 132 + c4 * 4] = Ws4[u];
    }
    for (int j = 0; j < 4; ++j) {
        int u = j * 256 + t;
        int r = u >> 5, c4 = u & 31;
        *(float4*)&lX[r * 132 + c4 * 4] = X4[bx * 1024 + u];
    }
    __syncthreads();
    int r0 = (t >> 5) * 4, c0 = (t & 31) * 4;
    float acc[4][4];
#pragma unroll
    for (int i = 0; i < 4; ++i)
#pragma unroll
        for (int j = 0; j < 4; ++j) acc[i][j] = 0.f;
#pragma unroll 4
    for (int k = 0; k < 128; ++k) {
        float4 wv = *(const float4*)&lWs[k * 132 + c0];
        float x0 = lX[(r0 + 0) * 132 + k];
        float x1 = lX[(r0 + 1) * 132 + k];
        float x2 = lX[(r0 + 2) * 132 + k];
        float x3 = lX[(r0 + 3) * 132 + k];
#pragma unroll
        for (int j = 0; j < 4; ++j) {
            acc[0][j] += x0 * ((const float*)&wv)[j];
            acc[1][j] += x1 * ((const float*)&wv)[j];
            acc[2][j] += x2 * ((const float*)&wv)[j];
            acc[3][j] += x3 * ((const float*)&wv)[j];
        }
    }
    __syncthreads();   // all lWs reads done; safe to overlay
    float* lT = lWs;   // [d=128][r=32] pad 33
#pragma unroll
    for (int i = 0; i < 4; ++i)
#pragma unroll
        for (int j = 0; j < 4; ++j) lT[(c0 + j) * 33 + r0 + i] = acc[i][j];
    __syncthreads();
    // s1/s2: 4 threads per row (threads 0..127)
    if (t < 128) {
        int r = t >> 2, q = t & 3;
        float s1 = 0.f, s2 = 0.f;
        for (int j = 0; j < 32; ++j) {
            int d = q * 32 + j;
            float v = lT[d * 33 + r];
            s1 += v * la[d];
            s2 += v * la[128 + d];
        }
        s1 += __shfl_xor(s1, 1); s1 += __shfl_xor(s1, 2);
        s2 += __shfl_xor(s2, 1); s2 += __shfl_xor(s2, 2);
        if (q == 0) {
            int i = i0 + r;
            C1[i]  = __expf(s1);
            C1s[i] = __expf(0.2f * s1);
            u32 pe = (u32)f2bf(__expf(s2));
            u32 ne = (u32)f2bf(__expf(0.2f * s2));
            E2bf[i] = pe | (ne << 16);
        }
    }
    // WhT: thread t -> d=t>>1, half hf=t&1: 16 contiguous bf16 (32 B)
    int d = t >> 1, hf = t & 1;
    __attribute__((aligned(16))) ushort tmp[16];
#pragma unroll
    for (int s = 0; s < 16; ++s) tmp[s] = f2bf(lT[d * 33 + hf * 16 + s]);
    uint4* dst = (uint4*)&WhT[(size_t)d * NN + i0 + hf * 16];
    const uint4* srcv = (const uint4*)tmp;
    dst[0] = srcv[0];
    dst[1] = srcv[1];
}

// ---------------- K3: masked-softmax GEMM ----------------
// grid (128 rowblocks, 4 ksplit) x 1024 thr (16 waves: g=wv&3 rowgroup 16 rows,
// h=wv>>2 col-quarter cc={2h,2h+1}). KT=64 tiles. A-frags: direct per-lane
// global_load_dwordx4 (line-covered). B: double-buffered LDS DMA (L2-resident
// WhT), 1 instr/wave/tile. E2: bf16-packed pair, loaded once to LDS.
// 40 KB LDS -> 2 blocks/CU (100% occ); co-resident block hides barrier drains.
// Row sums via MFMA vs all-ones B. w = max(c1*e^{s2}, c1s*e^{.2 s2}) * mask.
__global__ __launch_bounds__(1024, 8) void k3_main(
    const int* __restrict__ A, const ushort* __restrict__ WhT,
    const float* __restrict__ C1, const float* __restrict__ C1s,
    const u32* __restrict__ E2bf, float* __restrict__ Hp,
    float* __restrict__ Lp) {

    __shared__ __align__(16) ushort lB[2][16][64][8];   // [buf][cc*2+tp][lane][8] 32 KB
    __shared__ u32 lE[2048];                            // 8 KB

    int tid = threadIdx.x;
    int lane = tid & 63;
    int wv = tid >> 6;
    int g = wv & 3;
    int h = wv >> 2;
    int n = lane & 15;
    int kg = lane >> 4;

    int bx = blockIdx.x;
    int kb = blockIdx.y;
    int row = bx * 64 + g * 16 + n;
    int kbase = kb * 2048;

    // E2 slice -> LDS (once)
    lE[tid] = E2bf[kbase + tid];
    lE[tid + 1024] = E2bf[kbase + tid + 1024];

    float c1 = C1[row], c1s = C1s[row];
    const int* Arow = A + (size_t)row * NN + kbase + kg * 8;

    // B staging: wave wv stages chunk (cc_s = wv&7, tp_s = wv>>3)
    int cc_s = wv & 7, tp_s = wv >> 3;
    const ushort* srcB = WhT + (size_t)(cc_s * 16 + n) * NN + kbase + tp_s * 32 + kg * 8;
    ushort* dstB0 = &lB[0][cc_s * 2 + tp_s][lane][0];
    ushort* dstB1 = &lB[1][cc_s * 2 + tp_s][lane][0];

    short8 ones;
#pragma unroll
    for (int j = 0; j < 8; ++j) ones[j] = (short)0x3F80;

    f32x4 acc0 = (f32x4){0.f, 0.f, 0.f, 0.f};
    f32x4 acc1 = (f32x4){0.f, 0.f, 0.f, 0.f};
    f32x4 accl = (f32x4){0.f, 0.f, 0.f, 0.f};

    async_ld16(srcB, dstB0);   // prologue: tile 0 -> buf 0
    __syncthreads();           // also covers lE writes

    for (int kt = 0; kt < 32; ++kt) {
        int b = kt & 1;
        const int* Ak = Arow + kt * 64;
        int4 a00 = *(const int4*)(Ak);          // tp0, k kg*8..+3
        int4 a01 = *(const int4*)(Ak + 4);      // tp0, +4..7
        int4 a10 = *(const int4*)(Ak + 32);     // tp1
        int4 a11 = *(const int4*)(Ak + 36);
        if (kt < 31)                            // issued after A-loads: A-use leaves DMA in flight
            async_ld16(srcB + (kt + 1) * 64, b ? dstB0 : dstB1);
#pragma unroll
        for (int tp = 0; tp < 2; ++tp) {
            int ke = kt * 64 + tp * 32 + kg * 8;
            uint4 e0 = *(const uint4*)&lE[ke];
            uint4 e1 = *(const uint4*)&lE[ke + 4];
            int am[8];
            *(int4*)(am) = tp ? a10 : a00;
            *(int4*)(am + 4) = tp ? a11 : a01;
            u32 ev[8];
            *(uint4*)(ev) = e0; *(uint4*)(ev + 4) = e1;
            short8 af;
#pragma unroll
            for (int u = 0; u < 8; ++u) {
                float ep = asf(ev[u] << 16);
                float en = asf(ev[u] & 0xFFFF0000u);
                float w = fmaxf(c1 * ep, c1s * en);
                w = am[u] ? w : 0.f;
                af[u] = (short)f2bf(w);
            }
            short8 b0 = *(const short8*)&lB[b][(2 * h + 0) * 2 + tp][lane][0];
            short8 b1 = *(const short8*)&lB[b][(2 * h + 1) * 2 + tp][lane][0];
            acc0 = __builtin_amdgcn_mfma_f32_16x16x32_bf16(af, b0, acc0, 0, 0, 0);
            acc1 = __builtin_amdgcn_mfma_f32_16x16x32_bf16(af, b1, acc1, 0, 0, 0);
            accl = __builtin_amdgcn_mfma_f32_16x16x32_bf16(af, ones, accl, 0, 0, 0);
        }
        __syncthreads();
    }

    // epilogue. C/D layout: col = lane&15, row = (lane>>4)*4 + reg  [m89]
    if (h == 0 && n == 0) {
#pragma unroll
        for (int r = 0; r < 4; ++r)
            Lp[(size_t)kb * NN + bx * 64 + g * 16 + kg * 4 + r] = accl[r];
    }
    float* Hpb = Hp + (size_t)kb * (NN * DD);
#pragma unroll
    for (int r = 0; r < 4; ++r) {
        int orow = bx * 64 + g * 16 + kg * 4 + r;
        Hpb[(size_t)orow * DD + h * 32 + n] = acc0[r];
        Hpb[(size_t)orow * DD + h * 32 + 16 + n] = acc1[r];
    }
}

// ---------------- K4: combine split-K partials, normalize ----------------
__global__ void k4_final(const float* __restrict__ Hp, const float* __restrict__ Lp,
                         float* __restrict__ out) {
    int idx = blockIdx.x * 256 + threadIdx.x;
    int i = idx >> 7;
    float sv = Hp[idx] + Hp[1048576 + idx] + Hp[2097152 + idx] + Hp[3145728 + idx];
    float l = Lp[i] + Lp[8192 + i] + Lp[16384 + i] + Lp[24576 + i];
    out[idx] = sv / l;
}

extern "C" void kernel_launch(void* const* d_in, const int* in_sizes, int n_in,
                              void* d_out, int out_size, void* d_ws, size_t ws_size,
                              hipStream_t stream) {
    const int*   A  = (const int*)d_in[0];
    const float* X  = (const float*)d_in[1];
    const float* Ws = (const float*)d_in[2];
    const float* a  = (const float*)d_in[3];
    float* out = (float*)d_out;

    char* ws = (char*)d_ws;
    ushort* WhT  = (ushort*)(ws);                        // 2 MB
    float*  C1   = (float*)(ws + (2u << 20));            // 32 KB
    float*  C1s  = (float*)(ws + (2u << 20) + (32u << 10));
    u32*    E2bf = (u32*)(ws + (2u << 20) + (64u << 10)); // 32 KB
    float*  Lp   = (float*)(ws + (2u << 20) + (96u << 10)); // 128 KB
    float*  Hp   = (float*)(ws + (4u << 20));            // 16 MB

    k1_fused<<<256, 256, 0, stream>>>(X, Ws, a, WhT, C1, C1s, E2bf);
    k3_main<<<dim3(128, 4), 1024, 0, stream>>>(A, WhT, C1, C1s, E2bf, Hp, Lp);
    k4_final<<<4096, 256, 0, stream>>>(Hp, Lp, out);
}